// Round 6
// baseline (397.046 us; speedup 1.0000x reference)
//
#include <hip/hip_runtime.h>
#include <stdint.h>

// Problem constants (from reference)
#define ROWS 4096
#define COLS 11008
#define NTOT (ROWS * COLS)          // 45,088,768
#define NV4  (NTOT / 4)             // 11,272,192 (COLS % 4 == 0)
#define COLS4 (COLS / 4)            // 2752

// high_num = int(n*0.1); 1-indexed order-statistic ranks
#define HIGH_NUM 4508876u
#define RANK_LO  (HIGH_NUM / 2u)                   // 2,254,438
#define RANK_HI  ((unsigned)NTOT - HIGH_NUM / 2u)  // 42,834,330

#define BLK 256
#define GRID 2048
#define NTILES 11008                 // NV4 / 1024 (tile = 1024 float4)

// Sampling: 1024 blocks x 1024 contiguous float4 = 4,194,304 samples (16 MB)
#define SAMPLES 4194304ull
#define RS_LO ((unsigned)(((unsigned long long)RANK_LO * SAMPLES) / (unsigned long long)NTOT))
#define RS_HI ((unsigned)(((unsigned long long)RANK_HI * SAMPLES) / (unsigned long long)NTOT))
#define M_S 4500u                    // +/-10 sigma sample-rank margin

#define FSPAN (2u << 20)             // coarse window span: 2 x 12-bit buckets (keys)
#define FBINS (1u << 19)             // fine sample hist: 4-key bins over FSPAN
#define WMAX  (1u << 19)             // passA element hist: full-key-res window cap

// ws layout (u32 words)
#define OFF_CLO   0                       // 64 slots: exact #elems key < kA_lo
#define OFF_CHI   64                      // 64 slots: exact #elems key < kA_hi
#define OFF_META  128  // [0]=wstart_lo [1]=wstart_hi [2]=kA_lo [3]=width_lo
                       // [4]=kA_hi [5]=width_hi [6]=Cs_lo [7]=Cs_hi
#define OFF_THR   144                     // 2 floats (exact thresholds)
#define OFF_LCT   160                     // ambiguous-list counter (1 word)
#define OFF_H1S   256                     // 4096 coarse sample hist
#define OFF_FCS   (OFF_H1S + 4096)        // 1024 fine-sample chunk sums (512/target)
#define OFF_WCS   (OFF_FCS + 1024)        // 1024 passA chunk sums (512/target)
#define OFF_FLO   8192                    // 2^19 fine sample hist (lo)
#define OFF_FHI   (OFF_FLO + FBINS)       // 2^19 fine sample hist (hi)
#define OFF_WLO   (OFF_FHI + FBINS)       // 2^19 passA element hist (lo)
#define OFF_WHI   (OFF_WLO + WMAX)        // 2^19 passA element hist (hi)
#define WS_ZERO   (OFF_WHI + WMAX)        // words to zero (~8.4 MB)
#define OFF_LIST  WS_ZERO                 // u64 pairs (xbits<<32 | elem_idx)
#define LCAP      (1536u * 1024u)         // compact list capacity (~8x expected 194K)
#define WS_WORDS  (OFF_LIST + 2u * LCAP)

#define LDSCAP 2048u                      // per-block LDS staging (16 KB, ~21x margin)

typedef float vfloat4 __attribute__((ext_vector_type(4)));

__device__ __forceinline__ unsigned f2key(float f) {
    unsigned u = __float_as_uint(f);
    return (u & 0x80000000u) ? ~u : (u | 0x80000000u);
}
__device__ __forceinline__ float key2f(unsigned key) {
    unsigned u = (key & 0x80000000u) ? (key & 0x7fffffffu) : ~key;
    return __uint_as_float(u);
}
// Exact qdq (IEEE div + nearest-even) — byte-identical to all passing rounds.
__device__ __forceinline__ float qdq(float xx, bool m, float sl, float zl, float sh, float zh) {
    float s  = m ? sl : sh;
    float z  = m ? zl : zh;
    float mq = m ? 1.0f : 255.0f;
    float q = rintf(xx / s) + z;
    q = fminf(fmaxf(q, 0.0f), mq);
    return s * (q - z);
}

// ---------- sample: coarse 12-bit key histogram of 4M samples ----------
__global__ void __launch_bounds__(BLK) sample_kernel(const float* __restrict__ x,
                                                     unsigned* __restrict__ ws) {
    __shared__ unsigned h[8192];
    for (int i = threadIdx.x; i < 8192; i += BLK) h[i] = 0u;
    __syncthreads();
    const float4* x4 = (const float4*)x;
    const unsigned base = blockIdx.x * 11008u;
    const int par = threadIdx.x & 1;
#pragma unroll
    for (int i = 0; i < 4; i++) {
        float4 v = x4[base + threadIdx.x + 256 * i];
        atomicAdd(&h[((f2key(v.x) >> 20) << 1) + par], 1u);
        atomicAdd(&h[((f2key(v.y) >> 20) << 1) + par], 1u);
        atomicAdd(&h[((f2key(v.z) >> 20) << 1) + par], 1u);
        atomicAdd(&h[((f2key(v.w) >> 20) << 1) + par], 1u);
    }
    __syncthreads();
    unsigned* hist = ws + OFF_H1S;
    for (int i = threadIdx.x; i < 4096; i += BLK) {
        unsigned c = h[2 * i] + h[2 * i + 1];
        if (c) atomicAdd(&hist[i], c);
    }
}

// ---------- scan_sample: coarse 2-bucket windows + below-window sample counts ----------
__global__ void __launch_bounds__(BLK) scan_sample_kernel(unsigned* __restrict__ ws) {
    __shared__ unsigned part[256];
    const unsigned* hist = ws + OFF_H1S;
    unsigned* meta = ws + OFF_META;
    int t = threadIdx.x;
    unsigned v[16];
    unsigned sum = 0u;
#pragma unroll
    for (int i = 0; i < 16; i++) { v[i] = hist[t * 16 + i]; sum += v[i]; }
    part[t] = sum;
    __syncthreads();
    for (int off = 1; off < 256; off <<= 1) {
        unsigned a = (t >= off) ? part[t - off] : 0u;
        __syncthreads();
        part[t] += a;
        __syncthreads();
    }
    unsigned incl = part[t];
    unsigned excl = incl - sum;
    unsigned ranks[2] = {RS_LO, RS_HI};
    for (int k = 0; k < 2; k++) {
        unsigned Rs = ranks[k];
        if (excl < Rs && incl >= Rs) {
            unsigned cum = excl;
            for (int i = 0; i < 16; i++) {
                if (cum + v[i] >= Rs) {
                    unsigned b = (unsigned)(t * 16 + i);
                    unsigned rel = Rs - cum;
                    unsigned wb = (2u * rel <= v[i]) ? (b > 0 ? b - 1 : 0) : b;
                    if (wb > 4094u) wb = 4094u;
                    meta[k] = wb << 20;                 // window start key
                    unsigned Cs = cum;                  // samples below bucket b
                    if (wb < b) Cs -= hist[b - 1];      // extend down one bucket
                    meta[6 + k] = Cs;                   // samples below wstart
                    break;
                }
                cum += v[i];
            }
        }
    }
}

// ---------- sample_fine: fine (4-key-bin) sample hist inside coarse windows ----------
__global__ void __launch_bounds__(BLK) sample_fine_kernel(const float* __restrict__ x,
                                                          unsigned* __restrict__ ws) {
    const unsigned w0 = __builtin_amdgcn_readfirstlane(ws[OFF_META + 0]);
    const unsigned w1 = __builtin_amdgcn_readfirstlane(ws[OFF_META + 1]);
    unsigned* f0 = ws + OFF_FLO;
    unsigned* f1 = ws + OFF_FHI;
    const float4* x4 = (const float4*)x;
    const unsigned base = blockIdx.x * 11008u;
#pragma unroll
    for (int i = 0; i < 4; i++) {
        float4 v = x4[base + threadIdx.x + 256 * i];
        float f[4] = {v.x, v.y, v.z, v.w};
#pragma unroll
        for (int c = 0; c < 4; c++) {
            unsigned key = f2key(f[c]);
            unsigned d0 = key - w0;
            if (d0 < FSPAN) atomicAdd(&f0[d0 >> 2], 1u);
            unsigned d1 = key - w1;
            if (d1 < FSPAN) atomicAdd(&f1[d1 >> 2], 1u);
        }
    }
}

// ---------- csum: 1024-entry chunk sums (generic) ----------
__global__ void __launch_bounds__(BLK) csum_kernel(const unsigned* __restrict__ src,
                                                   unsigned* __restrict__ dst) {
    const unsigned* p = src + (size_t)blockIdx.x * 1024;
    int t = threadIdx.x;
    unsigned s = p[t] + p[t + 256] + p[t + 512] + p[t + 768];
    __shared__ unsigned red[256];
    red[t] = s;
    for (int off = 128; off > 0; off >>= 1) {
        __syncthreads();
        if (t < off) red[t] += red[t + off];
    }
    if (t == 0) dst[blockIdx.x] = red[0];
}

// ---------- fine_scan: pick key cut-points [kA, kA+width) at +/-M_S sample ranks -------
__global__ void __launch_bounds__(BLK) fine_scan_kernel(unsigned* __restrict__ ws) {
    __shared__ unsigned part[256];
    __shared__ unsigned sT, sC, sR;
    __shared__ unsigned sBin[2];
    const int t = threadIdx.x;
    const int tgt = blockIdx.x;
    const unsigned* cs = ws + OFF_FCS + tgt * 512;
    unsigned c0 = cs[2 * t], c1 = cs[2 * t + 1];
    unsigned gsum = c0 + c1;
    part[t] = gsum;
    __syncthreads();
    for (int off = 1; off < 256; off <<= 1) {
        unsigned a = (t >= off) ? part[t - off] : 0u;
        __syncthreads();
        part[t] += a;
        __syncthreads();
    }
    if (t == 255) sT = part[255];
    __syncthreads();
    const unsigned T = sT;
    const unsigned incl = part[t], excl = incl - gsum;
    unsigned Rs = tgt ? RS_HI : RS_LO;
    unsigned Cs = ws[OFF_META + 6 + tgt];
    unsigned RsA = Rs - Cs;
    if (RsA < 1u) RsA = 1u;
    if (RsA > T) RsA = T;
    unsigned rA = (RsA > M_S) ? RsA - M_S : 1u;
    unsigned rB = RsA + M_S;
    if (rB > T) rB = T;

    for (int q = 0; q < 2; q++) {
        unsigned r = q ? rB : rA;
        if (excl < r && incl >= r) {
            if (excl + c0 >= r) { sC = 2u * t;      sR = r - excl; }
            else                { sC = 2u * t + 1u; sR = r - excl - c0; }
        }
        __syncthreads();
        unsigned chunk = sC, rr = sR;
        __syncthreads();
        const unsigned* hp = ws + OFF_FLO + (size_t)tgt * FBINS + (size_t)chunk * 1024;
        unsigned w[4];
        unsigned s2 = 0u;
#pragma unroll
        for (int i = 0; i < 4; i++) { w[i] = hp[t * 4 + i]; s2 += w[i]; }
        part[t] = s2;
        __syncthreads();
        for (int off = 1; off < 256; off <<= 1) {
            unsigned a = (t >= off) ? part[t - off] : 0u;
            __syncthreads();
            part[t] += a;
            __syncthreads();
        }
        unsigned incl2 = part[t], excl2 = incl2 - s2;
        if (excl2 < rr && incl2 >= rr) {
            unsigned cum = excl2;
            for (int i = 0; i < 4; i++) {
                if (cum + w[i] >= rr) { sBin[q] = chunk * 1024u + (unsigned)(t * 4 + i); break; }
                cum += w[i];
            }
        }
        __syncthreads();
    }
    if (t == 0) {
        unsigned wstart = ws[OFF_META + tgt];
        unsigned kA = wstart + sBin[0] * 4u;
        unsigned kB = wstart + (sBin[1] + 1u) * 4u;
        unsigned width = kB - kA;
        if (width > WMAX) width = WMAX;
        ws[OFF_META + 2 + 2 * tgt] = kA;
        ws[OFF_META + 3 + 2 * tgt] = width;
    }
}

// ---------- passAQ: FUSED exact-count/hist pass + quantized output write ----------
// R5: register double-buffer software pipeline. R3/R5 counters proved passAQ is
// latency-bound (VALU 44%, HBM 30%, both idle ~half the time): each iteration was
// [4 loads -> vmcnt(0) -> compute -> stores] with zero cross-tile overlap. Now
// tile k+1's 4 float4 loads are issued BEFORE tile k's compute, hiding ~900cy of
// HBM latency under ~800cy of compute. VGPR was 24 -> +32 in flight is free.
__global__ void __launch_bounds__(BLK) passAQ_kernel(const float* __restrict__ x,
                                                     const float* __restrict__ sl_,
                                                     const float* __restrict__ zl_,
                                                     const float* __restrict__ sh_,
                                                     const float* __restrict__ zh_,
                                                     unsigned* __restrict__ ws,
                                                     float* __restrict__ out) {
    const unsigned kAlo = __builtin_amdgcn_readfirstlane(ws[OFF_META + 2]);
    const unsigned wLo  = __builtin_amdgcn_readfirstlane(ws[OFF_META + 3]);
    const unsigned kAhi = __builtin_amdgcn_readfirstlane(ws[OFF_META + 4]);
    const unsigned wHi  = __builtin_amdgcn_readfirstlane(ws[OFF_META + 5]);
    unsigned* hLo = ws + OFF_WLO;
    unsigned* hHi = ws + OFF_WHI;

    __shared__ unsigned long long s_list[LDSCAP];
    __shared__ unsigned s_lct;
    __shared__ unsigned s_base;
    __shared__ unsigned red[256];
    if (threadIdx.x == 0) s_lct = 0u;
    __syncthreads();

    const float4* x4 = (const float4*)x;
    vfloat4* o4 = (vfloat4*)out;
    unsigned long long* list = (unsigned long long*)(ws + OFF_LIST);
    unsigned cLo = 0u, cHi = 0u;

    // prologue: load first tile (GRID <= NTILES so every block has >= 1 tile)
    unsigned tile = blockIdx.x;
    float4 vv[4];
    {
        const size_t b0 = (size_t)tile * 1024u + threadIdx.x;
        vv[0] = x4[b0];
        vv[1] = x4[b0 + 256];
        vv[2] = x4[b0 + 512];
        vv[3] = x4[b0 + 768];
    }

    for (;;) {
        // ---- issue NEXT tile's loads first (overlap with this tile's compute) --
        const unsigned ntile = tile + GRID;
        const bool has = (ntile < NTILES);       // block-uniform
        float4 nx[4];
        if (has) {
            const size_t nb = (size_t)ntile * 1024u + threadIdx.x;
            nx[0] = x4[nb];
            nx[1] = x4[nb + 256];
            nx[2] = x4[nb + 512];
            nx[3] = x4[nb + 768];
        }

        // ---- uniform per-tile row info (tile spans rows row0 .. row0+1) ----
        const unsigned eT   = tile * 4096u;                  // first element of tile
        const unsigned row0 = eT / (unsigned)COLS;           // uniform -> s_load
        const unsigned rowB = (row0 + 1u < (unsigned)ROWS) ? row0 + 1u : row0;
        const unsigned Bnd  = (row0 + 1u) * (unsigned)COLS;  // first element of next row
        const float sl0 = sl_[row0], sl1 = sl_[rowB];
        const float zl0 = zl_[row0], zl1 = zl_[rowB];
        const float sh0 = sh_[row0], sh1 = sh_[rowB];
        const float zh0 = zh_[row0], zh1 = zh_[rowB];

        const size_t base = (size_t)tile * 1024u + threadIdx.x;
#pragma unroll
        for (int u = 0; u < 4; u++) {
            unsigned j  = (unsigned)(base + 256u * u);       // float4 index
            unsigned e0 = j * 4u;                            // element index of .x
            float in[4] = {vv[u].x, vv[u].y, vv[u].z, vv[u].w};
            float r[4];
#pragma unroll
            for (int c = 0; c < 4; c++) {
                float xx = in[c];
                unsigned key = f2key(xx);
                cLo += (key < kAlo) ? 1u : 0u;
                cHi += (key < kAhi) ? 1u : 0u;
                unsigned d0 = key - kAlo;
                unsigned d1 = key - kAhi;
                bool a0 = d0 < wLo;
                bool a1 = d1 < wHi;
                bool hirow = (e0 + (unsigned)c) >= Bnd;
                float sl = hirow ? sl1 : sl0;
                float zl = hirow ? zl1 : zl0;
                float sh = hirow ? sh1 : sh0;
                float zh = hirow ? zh1 : zh0;
                bool m = (key > kAlo) && (key < kAhi);       // exact when !amb
                r[c] = qdq(xx, m, sl, zl, sh, zh);
                if (__builtin_expect(a0 | a1, 0)) {          // single rare branch
                    if (a0) atomicAdd(&hLo[d0], 1u);
                    if (a1) atomicAdd(&hHi[d1], 1u);
                    unsigned pos = atomicAdd(&s_lct, 1u);    // LDS atomic: block-local
                    unsigned long long ent =
                        ((unsigned long long)__float_as_uint(xx) << 32)
                        | (unsigned long long)(e0 + (unsigned)c);
                    if (pos < LDSCAP) {
                        s_list[pos] = ent;
                    } else {                                 // safety spill (never in practice)
                        unsigned gpos = atomicAdd(&ws[OFF_LCT], 1u);
                        if (gpos < LCAP) list[gpos] = ent;
                    }
                }
            }
            vfloat4 rv = {r[0], r[1], r[2], r[3]};
            __builtin_nontemporal_store(rv, &o4[j]);
        }

        if (!has) break;
        tile = ntile;
        vv[0] = nx[0]; vv[1] = nx[1]; vv[2] = nx[2]; vv[3] = nx[3];
    }

    // exact below-kA counts
    red[threadIdx.x] = cLo;
    for (int off = 128; off > 0; off >>= 1) {
        __syncthreads();
        if (threadIdx.x < off) red[threadIdx.x] += red[threadIdx.x + off];
    }
    if (threadIdx.x == 0) atomicAdd(&ws[OFF_CLO + (blockIdx.x & 63)], red[0]);
    __syncthreads();
    red[threadIdx.x] = cHi;
    for (int off = 128; off > 0; off >>= 1) {
        __syncthreads();
        if (threadIdx.x < off) red[threadIdx.x] += red[threadIdx.x + off];
    }
    if (threadIdx.x == 0) atomicAdd(&ws[OFF_CHI + (blockIdx.x & 63)], red[0]);

    // flush ambiguous list: one global atomic per block, coalesced copy
    __syncthreads();
    unsigned n = s_lct;
    if (n > LDSCAP) n = LDSCAP;
    if (threadIdx.x == 0) s_base = atomicAdd(&ws[OFF_LCT], n);
    __syncthreads();
    unsigned gbase = s_base;
    for (unsigned i = threadIdx.x; i < n; i += BLK) {
        unsigned pos = gbase + i;
        if (pos < LCAP) list[pos] = s_list[i];
    }
}

// ---------- scanB: exact rank select inside the narrow window -> thresholds ----------
__global__ void __launch_bounds__(BLK) scanB_kernel(unsigned* __restrict__ ws) {
    __shared__ unsigned part[256];
    __shared__ unsigned s_C, s_chunk, s_r;
    const int t = threadIdx.x;
    const int tgt = blockIdx.x;
    float* thr = (float*)(ws + OFF_THR);

    part[t] = (t < 64) ? ws[(tgt ? OFF_CHI : OFF_CLO) + t] : 0u;
    for (int off = 128; off > 0; off >>= 1) {
        __syncthreads();
        if (t < off) part[t] += part[t + off];
    }
    if (t == 0) s_C = part[0];
    __syncthreads();
    const unsigned RANK = tgt ? RANK_HI : RANK_LO;
    const unsigned R = RANK - s_C;    // 1-indexed residual inside window
    __syncthreads();

    const unsigned* cs = ws + OFF_WCS + tgt * 512;
    unsigned c0 = cs[2 * t], c1 = cs[2 * t + 1];
    unsigned gsum = c0 + c1;
    part[t] = gsum;
    __syncthreads();
    for (int off = 1; off < 256; off <<= 1) {
        unsigned a = (t >= off) ? part[t - off] : 0u;
        __syncthreads();
        part[t] += a;
        __syncthreads();
    }
    unsigned incl = part[t], excl = incl - gsum;
    if (excl < R && incl >= R) {
        if (excl + c0 >= R) { s_chunk = 2u * t;      s_r = R - excl; }
        else                { s_chunk = 2u * t + 1u; s_r = R - excl - c0; }
    }
    __syncthreads();
    unsigned chunk = s_chunk, rr = s_r;
    __syncthreads();

    const unsigned* hp = ws + (tgt ? OFF_WHI : OFF_WLO) + (size_t)chunk * 1024;
    unsigned w[4];
    unsigned s2 = 0u;
#pragma unroll
    for (int i = 0; i < 4; i++) { w[i] = hp[t * 4 + i]; s2 += w[i]; }
    part[t] = s2;
    __syncthreads();
    for (int off = 1; off < 256; off <<= 1) {
        unsigned a = (t >= off) ? part[t - off] : 0u;
        __syncthreads();
        part[t] += a;
        __syncthreads();
    }
    unsigned incl2 = part[t], excl2 = incl2 - s2;
    if (excl2 < rr && incl2 >= rr) {
        unsigned cum = excl2;
        for (int i = 0; i < 4; i++) {
            if (cum + w[i] >= rr) {
                unsigned key = ws[OFF_META + 2 + 2 * tgt] + chunk * 1024u + (unsigned)(t * 4 + i);
                thr[tgt] = key2f(key);
                break;
            }
            cum += w[i];
        }
    }
}

// ---------- fixup: rewrite ambiguous elements with exact thresholds ----------
__global__ void __launch_bounds__(BLK) fixup_kernel(const float* __restrict__ sl_,
                                                    const float* __restrict__ zl_,
                                                    const float* __restrict__ sh_,
                                                    const float* __restrict__ zh_,
                                                    const unsigned* __restrict__ ws,
                                                    float* __restrict__ out) {
    const float lowT  = __uint_as_float(__builtin_amdgcn_readfirstlane(ws[OFF_THR + 0]));
    const float highT = __uint_as_float(__builtin_amdgcn_readfirstlane(ws[OFF_THR + 1]));
    unsigned n = ws[OFF_LCT];
    if (n > LCAP) n = LCAP;
    const unsigned long long* list = (const unsigned long long*)(ws + OFF_LIST);

    for (unsigned i = blockIdx.x * BLK + threadIdx.x; i < n; i += gridDim.x * BLK) {
        unsigned long long p = list[i];
        unsigned idx = (unsigned)p;
        float xx = __uint_as_float((unsigned)(p >> 32));
        unsigned row = idx / (unsigned)COLS;
        bool m = (xx > lowT) && (xx < highT);   // exact reference semantics
        out[idx] = qdq(xx, m, sl_[row], zl_[row], sh_[row], zh_[row]);
    }
}

extern "C" void kernel_launch(void* const* d_in, const int* in_sizes, int n_in,
                              void* d_out, int out_size, void* d_ws, size_t ws_size,
                              hipStream_t stream) {
    const float* x  = (const float*)d_in[0];
    const float* sl = (const float*)d_in[1];
    const float* zl = (const float*)d_in[2];
    const float* sh = (const float*)d_in[3];
    const float* zh = (const float*)d_in[4];
    float* out = (float*)d_out;
    unsigned* ws = (unsigned*)d_ws;

    (void)hipMemsetAsync(d_ws, 0, (size_t)WS_ZERO * 4, stream);   // ~8.4 MB

    sample_kernel<<<1024, BLK, 0, stream>>>(x, ws);
    scan_sample_kernel<<<1, BLK, 0, stream>>>(ws);
    sample_fine_kernel<<<1024, BLK, 0, stream>>>(x, ws);
    csum_kernel<<<1024, BLK, 0, stream>>>(ws + OFF_FLO, ws + OFF_FCS);
    fine_scan_kernel<<<2, BLK, 0, stream>>>(ws);
    passAQ_kernel<<<GRID, BLK, 0, stream>>>(x, sl, zl, sh, zh, ws, out);
    csum_kernel<<<1024, BLK, 0, stream>>>(ws + OFF_WLO, ws + OFF_WCS);
    scanB_kernel<<<2, BLK, 0, stream>>>(ws);
    fixup_kernel<<<256, BLK, 0, stream>>>(sl, zl, sh, zh, ws, out);
}

// Round 7
// 395.131 us; speedup vs baseline: 1.0048x; 1.0048x over previous
//
#include <hip/hip_runtime.h>
#include <stdint.h>

// Problem constants (from reference)
#define ROWS 4096
#define COLS 11008
#define NTOT (ROWS * COLS)          // 45,088,768
#define NV4  (NTOT / 4)             // 11,272,192 (COLS % 4 == 0)
#define COLS4 (COLS / 4)            // 2752

// high_num = int(n*0.1); 1-indexed order-statistic ranks
#define HIGH_NUM 4508876u
#define RANK_LO  (HIGH_NUM / 2u)                   // 2,254,438
#define RANK_HI  ((unsigned)NTOT - HIGH_NUM / 2u)  // 42,834,330

#define BLK 256
#define GRID 2048
#define NTILES 11008                 // NV4 / 1024 (tile = 1024 float4)

// Sampling: 1024 blocks x 1024 contiguous float4 = 4,194,304 samples (16 MB)
#define SAMPLES 4194304ull
#define RS_LO ((unsigned)(((unsigned long long)RANK_LO * SAMPLES) / (unsigned long long)NTOT))
#define RS_HI ((unsigned)(((unsigned long long)RANK_HI * SAMPLES) / (unsigned long long)NTOT))
#define M_S 4500u                    // +/-10 sigma sample-rank margin

#define FSPAN (2u << 20)             // coarse window span: 2 x 12-bit buckets (keys)
#define FBINS (1u << 19)             // fine sample hist: 4-key bins over FSPAN
#define WMAX  (1u << 19)             // passA element hist: full-key-res window cap

// ws layout (u32 words)
#define OFF_CLO   0                       // 64 slots: exact #elems key < kA_lo
#define OFF_CHI   64                      // 64 slots: exact #elems key < kA_hi
#define OFF_META  128  // [0]=wstart_lo [1]=wstart_hi [2]=kA_lo [3]=width_lo
                       // [4]=kA_hi [5]=width_hi [6]=Cs_lo [7]=Cs_hi
#define OFF_THR   144                     // 2 floats (exact thresholds)
#define OFF_LCT   160                     // ambiguous-list counter (1 word)
#define OFF_H1S   256                     // 4096 coarse sample hist
#define OFF_FCS   (OFF_H1S + 4096)        // 1024 fine-sample chunk sums (512/target)
#define OFF_WCS   (OFF_FCS + 1024)        // 1024 passA chunk sums (512/target)
#define OFF_FLO   8192                    // 2^19 fine sample hist (lo)
#define OFF_FHI   (OFF_FLO + FBINS)       // 2^19 fine sample hist (hi)
#define OFF_WLO   (OFF_FHI + FBINS)       // 2^19 passA element hist (lo)
#define OFF_WHI   (OFF_WLO + WMAX)        // 2^19 passA element hist (hi)
#define WS_ZERO   (OFF_WHI + WMAX)        // words to zero (~8.4 MB)
#define OFF_LIST  WS_ZERO                 // u64 pairs (xbits<<32 | elem_idx)
#define LCAP      (1536u * 1024u)         // compact list capacity (~8x expected 194K)
#define WS_WORDS  (OFF_LIST + 2u * LCAP)

#define LDSCAP 2048u                      // per-block LDS staging (16 KB, ~21x margin)

typedef float vfloat4 __attribute__((ext_vector_type(4)));

__device__ __forceinline__ unsigned f2key(float f) {
    unsigned u = __float_as_uint(f);
    return (u & 0x80000000u) ? ~u : (u | 0x80000000u);
}
__device__ __forceinline__ float key2f(unsigned key) {
    unsigned u = (key & 0x80000000u) ? (key & 0x7fffffffu) : ~key;
    return __uint_as_float(u);
}
// Exact qdq (IEEE div + nearest-even) — byte-identical to all passing rounds.
__device__ __forceinline__ float qdq(float xx, bool m, float sl, float zl, float sh, float zh) {
    float s  = m ? sl : sh;
    float z  = m ? zl : zh;
    float mq = m ? 1.0f : 255.0f;
    float q = rintf(xx / s) + z;
    q = fminf(fmaxf(q, 0.0f), mq);
    return s * (q - z);
}

// ---------- sample: coarse 12-bit key histogram of 4M samples ----------
__global__ void __launch_bounds__(BLK) sample_kernel(const float* __restrict__ x,
                                                     unsigned* __restrict__ ws) {
    __shared__ unsigned h[8192];
    for (int i = threadIdx.x; i < 8192; i += BLK) h[i] = 0u;
    __syncthreads();
    const float4* x4 = (const float4*)x;
    const unsigned base = blockIdx.x * 11008u;
    const int par = threadIdx.x & 1;
#pragma unroll
    for (int i = 0; i < 4; i++) {
        float4 v = x4[base + threadIdx.x + 256 * i];
        atomicAdd(&h[((f2key(v.x) >> 20) << 1) + par], 1u);
        atomicAdd(&h[((f2key(v.y) >> 20) << 1) + par], 1u);
        atomicAdd(&h[((f2key(v.z) >> 20) << 1) + par], 1u);
        atomicAdd(&h[((f2key(v.w) >> 20) << 1) + par], 1u);
    }
    __syncthreads();
    unsigned* hist = ws + OFF_H1S;
    for (int i = threadIdx.x; i < 4096; i += BLK) {
        unsigned c = h[2 * i] + h[2 * i + 1];
        if (c) atomicAdd(&hist[i], c);
    }
}

// ---------- scan_sample: coarse 2-bucket windows + below-window sample counts ----------
__global__ void __launch_bounds__(BLK) scan_sample_kernel(unsigned* __restrict__ ws) {
    __shared__ unsigned part[256];
    const unsigned* hist = ws + OFF_H1S;
    unsigned* meta = ws + OFF_META;
    int t = threadIdx.x;
    unsigned v[16];
    unsigned sum = 0u;
#pragma unroll
    for (int i = 0; i < 16; i++) { v[i] = hist[t * 16 + i]; sum += v[i]; }
    part[t] = sum;
    __syncthreads();
    for (int off = 1; off < 256; off <<= 1) {
        unsigned a = (t >= off) ? part[t - off] : 0u;
        __syncthreads();
        part[t] += a;
        __syncthreads();
    }
    unsigned incl = part[t];
    unsigned excl = incl - sum;
    unsigned ranks[2] = {RS_LO, RS_HI};
    for (int k = 0; k < 2; k++) {
        unsigned Rs = ranks[k];
        if (excl < Rs && incl >= Rs) {
            unsigned cum = excl;
            for (int i = 0; i < 16; i++) {
                if (cum + v[i] >= Rs) {
                    unsigned b = (unsigned)(t * 16 + i);
                    unsigned rel = Rs - cum;
                    unsigned wb = (2u * rel <= v[i]) ? (b > 0 ? b - 1 : 0) : b;
                    if (wb > 4094u) wb = 4094u;
                    meta[k] = wb << 20;                 // window start key
                    unsigned Cs = cum;                  // samples below bucket b
                    if (wb < b) Cs -= hist[b - 1];      // extend down one bucket
                    meta[6 + k] = Cs;                   // samples below wstart
                    break;
                }
                cum += v[i];
            }
        }
    }
}

// ---------- sample_fine: fine (4-key-bin) sample hist inside coarse windows ----------
__global__ void __launch_bounds__(BLK) sample_fine_kernel(const float* __restrict__ x,
                                                          unsigned* __restrict__ ws) {
    const unsigned w0 = __builtin_amdgcn_readfirstlane(ws[OFF_META + 0]);
    const unsigned w1 = __builtin_amdgcn_readfirstlane(ws[OFF_META + 1]);
    unsigned* f0 = ws + OFF_FLO;
    unsigned* f1 = ws + OFF_FHI;
    const float4* x4 = (const float4*)x;
    const unsigned base = blockIdx.x * 11008u;
#pragma unroll
    for (int i = 0; i < 4; i++) {
        float4 v = x4[base + threadIdx.x + 256 * i];
        float f[4] = {v.x, v.y, v.z, v.w};
#pragma unroll
        for (int c = 0; c < 4; c++) {
            unsigned key = f2key(f[c]);
            unsigned d0 = key - w0;
            if (d0 < FSPAN) atomicAdd(&f0[d0 >> 2], 1u);
            unsigned d1 = key - w1;
            if (d1 < FSPAN) atomicAdd(&f1[d1 >> 2], 1u);
        }
    }
}

// ---------- csum: 1024-entry chunk sums (generic) ----------
__global__ void __launch_bounds__(BLK) csum_kernel(const unsigned* __restrict__ src,
                                                   unsigned* __restrict__ dst) {
    const unsigned* p = src + (size_t)blockIdx.x * 1024;
    int t = threadIdx.x;
    unsigned s = p[t] + p[t + 256] + p[t + 512] + p[t + 768];
    __shared__ unsigned red[256];
    red[t] = s;
    for (int off = 128; off > 0; off >>= 1) {
        __syncthreads();
        if (t < off) red[t] += red[t + off];
    }
    if (t == 0) dst[blockIdx.x] = red[0];
}

// ---------- fine_scan: pick key cut-points [kA, kA+width) at +/-M_S sample ranks -------
__global__ void __launch_bounds__(BLK) fine_scan_kernel(unsigned* __restrict__ ws) {
    __shared__ unsigned part[256];
    __shared__ unsigned sT, sC, sR;
    __shared__ unsigned sBin[2];
    const int t = threadIdx.x;
    const int tgt = blockIdx.x;
    const unsigned* cs = ws + OFF_FCS + tgt * 512;
    unsigned c0 = cs[2 * t], c1 = cs[2 * t + 1];
    unsigned gsum = c0 + c1;
    part[t] = gsum;
    __syncthreads();
    for (int off = 1; off < 256; off <<= 1) {
        unsigned a = (t >= off) ? part[t - off] : 0u;
        __syncthreads();
        part[t] += a;
        __syncthreads();
    }
    if (t == 255) sT = part[255];
    __syncthreads();
    const unsigned T = sT;
    const unsigned incl = part[t], excl = incl - gsum;
    unsigned Rs = tgt ? RS_HI : RS_LO;
    unsigned Cs = ws[OFF_META + 6 + tgt];
    unsigned RsA = Rs - Cs;
    if (RsA < 1u) RsA = 1u;
    if (RsA > T) RsA = T;
    unsigned rA = (RsA > M_S) ? RsA - M_S : 1u;
    unsigned rB = RsA + M_S;
    if (rB > T) rB = T;

    for (int q = 0; q < 2; q++) {
        unsigned r = q ? rB : rA;
        if (excl < r && incl >= r) {
            if (excl + c0 >= r) { sC = 2u * t;      sR = r - excl; }
            else                { sC = 2u * t + 1u; sR = r - excl - c0; }
        }
        __syncthreads();
        unsigned chunk = sC, rr = sR;
        __syncthreads();
        const unsigned* hp = ws + OFF_FLO + (size_t)tgt * FBINS + (size_t)chunk * 1024;
        unsigned w[4];
        unsigned s2 = 0u;
#pragma unroll
        for (int i = 0; i < 4; i++) { w[i] = hp[t * 4 + i]; s2 += w[i]; }
        part[t] = s2;
        __syncthreads();
        for (int off = 1; off < 256; off <<= 1) {
            unsigned a = (t >= off) ? part[t - off] : 0u;
            __syncthreads();
            part[t] += a;
            __syncthreads();
        }
        unsigned incl2 = part[t], excl2 = incl2 - s2;
        if (excl2 < rr && incl2 >= rr) {
            unsigned cum = excl2;
            for (int i = 0; i < 4; i++) {
                if (cum + w[i] >= rr) { sBin[q] = chunk * 1024u + (unsigned)(t * 4 + i); break; }
                cum += w[i];
            }
        }
        __syncthreads();
    }
    if (t == 0) {
        unsigned wstart = ws[OFF_META + tgt];
        unsigned kA = wstart + sBin[0] * 4u;
        unsigned kB = wstart + (sBin[1] + 1u) * 4u;
        unsigned width = kB - kA;
        if (width > WMAX) width = WMAX;
        ws[OFF_META + 2 + 2 * tgt] = kA;
        ws[OFF_META + 3 + 2 * tgt] = width;
    }
}

// ---------- passAQ: FUSED exact-count/hist pass + quantized output write ----------
// R6: (a) global hist atomics moved OUT of the streaming loop (done at flush from
// the staged s_list entries — identical multiset). Mechanism: global atomics share
// the vmcnt counter with loads; the per-tile s_waitcnt vmcnt(0) for x-loads also
// drained all outstanding cross-XCD atomic RMWs (~us-class stragglers), stalling
// every wave every tile. (b) next-tile register prefetch pinned with
// sched_barrier(0) so the compiler can't sink the loads (R5: VGPR 24->32 showed
// the unpinned prefetch was undone; expect ~50-60 VGPR now).
__global__ void __launch_bounds__(BLK) passAQ_kernel(const float* __restrict__ x,
                                                     const float* __restrict__ sl_,
                                                     const float* __restrict__ zl_,
                                                     const float* __restrict__ sh_,
                                                     const float* __restrict__ zh_,
                                                     unsigned* __restrict__ ws,
                                                     float* __restrict__ out) {
    const unsigned kAlo = __builtin_amdgcn_readfirstlane(ws[OFF_META + 2]);
    const unsigned wLo  = __builtin_amdgcn_readfirstlane(ws[OFF_META + 3]);
    const unsigned kAhi = __builtin_amdgcn_readfirstlane(ws[OFF_META + 4]);
    const unsigned wHi  = __builtin_amdgcn_readfirstlane(ws[OFF_META + 5]);
    unsigned* hLo = ws + OFF_WLO;
    unsigned* hHi = ws + OFF_WHI;

    __shared__ unsigned long long s_list[LDSCAP];
    __shared__ unsigned s_lct;
    __shared__ unsigned s_base;
    __shared__ unsigned red[256];
    if (threadIdx.x == 0) s_lct = 0u;
    __syncthreads();

    const float4* x4 = (const float4*)x;
    vfloat4* o4 = (vfloat4*)out;
    unsigned long long* list = (unsigned long long*)(ws + OFF_LIST);
    unsigned cLo = 0u, cHi = 0u;

    // prologue: load first tile (GRID <= NTILES so every block has >= 1 tile)
    unsigned tile = blockIdx.x;
    float4 vv[4];
    {
        const size_t b0 = (size_t)tile * 1024u + threadIdx.x;
        vv[0] = x4[b0];
        vv[1] = x4[b0 + 256];
        vv[2] = x4[b0 + 512];
        vv[3] = x4[b0 + 768];
    }

    for (;;) {
        // ---- issue NEXT tile's loads first, PINNED above the compute ----
        const unsigned ntile = tile + GRID;
        const bool has = (ntile < NTILES);       // block-uniform
        float4 nx[4];
        if (has) {
            const size_t nb = (size_t)ntile * 1024u + threadIdx.x;
            nx[0] = x4[nb];
            nx[1] = x4[nb + 256];
            nx[2] = x4[nb + 512];
            nx[3] = x4[nb + 768];
        }
        __builtin_amdgcn_sched_barrier(0);       // keep prefetch issued here

        // ---- uniform per-tile row info (tile spans rows row0 .. row0+1) ----
        const unsigned eT   = tile * 4096u;                  // first element of tile
        const unsigned row0 = eT / (unsigned)COLS;           // uniform -> s_load
        const unsigned rowB = (row0 + 1u < (unsigned)ROWS) ? row0 + 1u : row0;
        const unsigned Bnd  = (row0 + 1u) * (unsigned)COLS;  // first element of next row
        const float sl0 = sl_[row0], sl1 = sl_[rowB];
        const float zl0 = zl_[row0], zl1 = zl_[rowB];
        const float sh0 = sh_[row0], sh1 = sh_[rowB];
        const float zh0 = zh_[row0], zh1 = zh_[rowB];

        const size_t base = (size_t)tile * 1024u + threadIdx.x;
#pragma unroll
        for (int u = 0; u < 4; u++) {
            unsigned j  = (unsigned)(base + 256u * u);       // float4 index
            unsigned e0 = j * 4u;                            // element index of .x
            float in[4] = {vv[u].x, vv[u].y, vv[u].z, vv[u].w};
            float r[4];
#pragma unroll
            for (int c = 0; c < 4; c++) {
                float xx = in[c];
                unsigned key = f2key(xx);
                cLo += (key < kAlo) ? 1u : 0u;
                cHi += (key < kAhi) ? 1u : 0u;
                unsigned d0 = key - kAlo;
                unsigned d1 = key - kAhi;
                bool a0 = d0 < wLo;
                bool a1 = d1 < wHi;
                bool hirow = (e0 + (unsigned)c) >= Bnd;
                float sl = hirow ? sl1 : sl0;
                float zl = hirow ? zl1 : zl0;
                float sh = hirow ? sh1 : sh0;
                float zh = hirow ? zh1 : zh0;
                bool m = (key > kAlo) && (key < kAhi);       // exact when !amb
                r[c] = qdq(xx, m, sl, zl, sh, zh);
                if (__builtin_expect(a0 | a1, 0)) {          // single rare branch
                    // NO global atomics here — staged; hist done at flush.
                    unsigned pos = atomicAdd(&s_lct, 1u);    // LDS atomic: block-local
                    unsigned long long ent =
                        ((unsigned long long)__float_as_uint(xx) << 32)
                        | (unsigned long long)(e0 + (unsigned)c);
                    if (pos < LDSCAP) {
                        s_list[pos] = ent;
                    } else {                                 // safety spill (never in practice)
                        if (a0) atomicAdd(&hLo[d0], 1u);
                        if (a1) atomicAdd(&hHi[d1], 1u);
                        unsigned gpos = atomicAdd(&ws[OFF_LCT], 1u);
                        if (gpos < LCAP) list[gpos] = ent;
                    }
                }
            }
            vfloat4 rv = {r[0], r[1], r[2], r[3]};
            __builtin_nontemporal_store(rv, &o4[j]);
        }

        if (!has) break;
        tile = ntile;
        vv[0] = nx[0]; vv[1] = nx[1]; vv[2] = nx[2]; vv[3] = nx[3];
    }

    // exact below-kA counts
    red[threadIdx.x] = cLo;
    for (int off = 128; off > 0; off >>= 1) {
        __syncthreads();
        if (threadIdx.x < off) red[threadIdx.x] += red[threadIdx.x + off];
    }
    if (threadIdx.x == 0) atomicAdd(&ws[OFF_CLO + (blockIdx.x & 63)], red[0]);
    __syncthreads();
    red[threadIdx.x] = cHi;
    for (int off = 128; off > 0; off >>= 1) {
        __syncthreads();
        if (threadIdx.x < off) red[threadIdx.x] += red[threadIdx.x + off];
    }
    if (threadIdx.x == 0) atomicAdd(&ws[OFF_CHI + (blockIdx.x & 63)], red[0]);

    // flush: batched hist updates from staged entries, then compact-list append
    __syncthreads();
    unsigned n = s_lct;
    if (n > LDSCAP) n = LDSCAP;
    for (unsigned i = threadIdx.x; i < n; i += BLK) {
        unsigned long long e = s_list[i];
        unsigned key = f2key(__uint_as_float((unsigned)(e >> 32)));
        unsigned d0 = key - kAlo;
        if (d0 < wLo) atomicAdd(&hLo[d0], 1u);
        unsigned d1 = key - kAhi;
        if (d1 < wHi) atomicAdd(&hHi[d1], 1u);
    }
    if (threadIdx.x == 0) s_base = atomicAdd(&ws[OFF_LCT], n);
    __syncthreads();
    unsigned gbase = s_base;
    for (unsigned i = threadIdx.x; i < n; i += BLK) {
        unsigned pos = gbase + i;
        if (pos < LCAP) list[pos] = s_list[i];
    }
}

// ---------- scanB: exact rank select inside the narrow window -> thresholds ----------
__global__ void __launch_bounds__(BLK) scanB_kernel(unsigned* __restrict__ ws) {
    __shared__ unsigned part[256];
    __shared__ unsigned s_C, s_chunk, s_r;
    const int t = threadIdx.x;
    const int tgt = blockIdx.x;
    float* thr = (float*)(ws + OFF_THR);

    part[t] = (t < 64) ? ws[(tgt ? OFF_CHI : OFF_CLO) + t] : 0u;
    for (int off = 128; off > 0; off >>= 1) {
        __syncthreads();
        if (t < off) part[t] += part[t + off];
    }
    if (t == 0) s_C = part[0];
    __syncthreads();
    const unsigned RANK = tgt ? RANK_HI : RANK_LO;
    const unsigned R = RANK - s_C;    // 1-indexed residual inside window
    __syncthreads();

    const unsigned* cs = ws + OFF_WCS + tgt * 512;
    unsigned c0 = cs[2 * t], c1 = cs[2 * t + 1];
    unsigned gsum = c0 + c1;
    part[t] = gsum;
    __syncthreads();
    for (int off = 1; off < 256; off <<= 1) {
        unsigned a = (t >= off) ? part[t - off] : 0u;
        __syncthreads();
        part[t] += a;
        __syncthreads();
    }
    unsigned incl = part[t], excl = incl - gsum;
    if (excl < R && incl >= R) {
        if (excl + c0 >= R) { s_chunk = 2u * t;      s_r = R - excl; }
        else                { s_chunk = 2u * t + 1u; s_r = R - excl - c0; }
    }
    __syncthreads();
    unsigned chunk = s_chunk, rr = s_r;
    __syncthreads();

    const unsigned* hp = ws + (tgt ? OFF_WHI : OFF_WLO) + (size_t)chunk * 1024;
    unsigned w[4];
    unsigned s2 = 0u;
#pragma unroll
    for (int i = 0; i < 4; i++) { w[i] = hp[t * 4 + i]; s2 += w[i]; }
    part[t] = s2;
    __syncthreads();
    for (int off = 1; off < 256; off <<= 1) {
        unsigned a = (t >= off) ? part[t - off] : 0u;
        __syncthreads();
        part[t] += a;
        __syncthreads();
    }
    unsigned incl2 = part[t], excl2 = incl2 - s2;
    if (excl2 < rr && incl2 >= rr) {
        unsigned cum = excl2;
        for (int i = 0; i < 4; i++) {
            if (cum + w[i] >= rr) {
                unsigned key = ws[OFF_META + 2 + 2 * tgt] + chunk * 1024u + (unsigned)(t * 4 + i);
                thr[tgt] = key2f(key);
                break;
            }
            cum += w[i];
        }
    }
}

// ---------- fixup: rewrite ambiguous elements with exact thresholds ----------
__global__ void __launch_bounds__(BLK) fixup_kernel(const float* __restrict__ sl_,
                                                    const float* __restrict__ zl_,
                                                    const float* __restrict__ sh_,
                                                    const float* __restrict__ zh_,
                                                    const unsigned* __restrict__ ws,
                                                    float* __restrict__ out) {
    const float lowT  = __uint_as_float(__builtin_amdgcn_readfirstlane(ws[OFF_THR + 0]));
    const float highT = __uint_as_float(__builtin_amdgcn_readfirstlane(ws[OFF_THR + 1]));
    unsigned n = ws[OFF_LCT];
    if (n > LCAP) n = LCAP;
    const unsigned long long* list = (const unsigned long long*)(ws + OFF_LIST);

    for (unsigned i = blockIdx.x * BLK + threadIdx.x; i < n; i += gridDim.x * BLK) {
        unsigned long long p = list[i];
        unsigned idx = (unsigned)p;
        float xx = __uint_as_float((unsigned)(p >> 32));
        unsigned row = idx / (unsigned)COLS;
        bool m = (xx > lowT) && (xx < highT);   // exact reference semantics
        out[idx] = qdq(xx, m, sl_[row], zl_[row], sh_[row], zh_[row]);
    }
}

extern "C" void kernel_launch(void* const* d_in, const int* in_sizes, int n_in,
                              void* d_out, int out_size, void* d_ws, size_t ws_size,
                              hipStream_t stream) {
    const float* x  = (const float*)d_in[0];
    const float* sl = (const float*)d_in[1];
    const float* zl = (const float*)d_in[2];
    const float* sh = (const float*)d_in[3];
    const float* zh = (const float*)d_in[4];
    float* out = (float*)d_out;
    unsigned* ws = (unsigned*)d_ws;

    (void)hipMemsetAsync(d_ws, 0, (size_t)WS_ZERO * 4, stream);   // ~8.4 MB

    sample_kernel<<<1024, BLK, 0, stream>>>(x, ws);
    scan_sample_kernel<<<1, BLK, 0, stream>>>(ws);
    sample_fine_kernel<<<1024, BLK, 0, stream>>>(x, ws);
    csum_kernel<<<1024, BLK, 0, stream>>>(ws + OFF_FLO, ws + OFF_FCS);
    fine_scan_kernel<<<2, BLK, 0, stream>>>(ws);
    passAQ_kernel<<<GRID, BLK, 0, stream>>>(x, sl, zl, sh, zh, ws, out);
    csum_kernel<<<1024, BLK, 0, stream>>>(ws + OFF_WLO, ws + OFF_WCS);
    scanB_kernel<<<2, BLK, 0, stream>>>(ws);
    fixup_kernel<<<256, BLK, 0, stream>>>(sl, zl, sh, zh, ws, out);
}

// Round 8
// 386.589 us; speedup vs baseline: 1.0270x; 1.0221x over previous
//
#include <hip/hip_runtime.h>
#include <stdint.h>

// Problem constants (from reference)
#define ROWS 4096
#define COLS 11008
#define NTOT (ROWS * COLS)          // 45,088,768
#define NV4  (NTOT / 4)             // 11,272,192 (COLS % 4 == 0)
#define COLS4 (COLS / 4)            // 2752

// high_num = int(n*0.1); 1-indexed order-statistic ranks
#define HIGH_NUM 4508876u
#define RANK_LO  (HIGH_NUM / 2u)                   // 2,254,438
#define RANK_HI  ((unsigned)NTOT - HIGH_NUM / 2u)  // 42,834,330

#define BLK 256
#define GRID 2048
#define NTILES 11008                 // NV4 / 1024 (tile = 1024 float4)

// Sampling: 1024 blocks x 1024 contiguous float4 = 4,194,304 samples (16 MB)
#define SAMPLES 4194304ull
#define RS_LO ((unsigned)(((unsigned long long)RANK_LO * SAMPLES) / (unsigned long long)NTOT))
#define RS_HI ((unsigned)(((unsigned long long)RANK_HI * SAMPLES) / (unsigned long long)NTOT))
#define M_S 4500u                    // +/-10 sigma sample-rank margin

#define FSPAN (2u << 20)             // coarse window span: 2 x 12-bit buckets (keys)
#define FBINS (1u << 19)             // fine sample hist: 4-key bins over FSPAN
#define WMAX  (1u << 19)             // passA element hist: full-key-res window cap

// ws layout (u32 words)
#define OFF_CLO   0                       // 64 slots: exact #elems key < kA_lo
#define OFF_CHI   64                      // 64 slots: exact #elems key < kA_hi
#define OFF_META  128  // [0]=wstart_lo [1]=wstart_hi [2]=kA_lo [3]=width_lo
                       // [4]=kA_hi [5]=width_hi [6]=Cs_lo [7]=Cs_hi
#define OFF_THR   144                     // 2 floats (exact thresholds)
#define OFF_LCT   160                     // ambiguous-list counter (1 word)
#define OFF_H1S   256                     // 4096 coarse sample hist
#define OFF_FCS   (OFF_H1S + 4096)        // 1024 fine-sample chunk sums (512/target)
#define OFF_WCS   (OFF_FCS + 1024)        // 1024 passA chunk sums (512/target)
#define OFF_FLO   8192                    // 2^19 fine sample hist (lo)
#define OFF_FHI   (OFF_FLO + FBINS)       // 2^19 fine sample hist (hi)
#define OFF_WLO   (OFF_FHI + FBINS)       // 2^19 passA element hist (lo)
#define OFF_WHI   (OFF_WLO + WMAX)        // 2^19 passA element hist (hi)
#define WS_ZERO   (OFF_WHI + WMAX)        // words to zero (~8.4 MB)
#define OFF_LIST  WS_ZERO                 // u64 pairs (xbits<<32 | elem_idx)
#define LCAP      (1536u * 1024u)         // compact list capacity (~8x expected 194K)
#define WS_WORDS  (OFF_LIST + 2u * LCAP)

#define LDSCAP 2048u                      // per-block LDS staging (16 KB, ~21x margin)

typedef float vfloat4 __attribute__((ext_vector_type(4)));

__device__ __forceinline__ unsigned f2key(float f) {
    unsigned u = __float_as_uint(f);
    return (u & 0x80000000u) ? ~u : (u | 0x80000000u);
}
__device__ __forceinline__ float key2f(unsigned key) {
    unsigned u = (key & 0x80000000u) ? (key & 0x7fffffffu) : ~key;
    return __uint_as_float(u);
}
// Exact qdq (IEEE div + nearest-even) — byte-identical to all passing rounds.
__device__ __forceinline__ float qdq(float xx, bool m, float sl, float zl, float sh, float zh) {
    float s  = m ? sl : sh;
    float z  = m ? zl : zh;
    float mq = m ? 1.0f : 255.0f;
    float q = rintf(xx / s) + z;
    q = fminf(fmaxf(q, 0.0f), mq);
    return s * (q - z);
}

// ---------- sample: coarse 12-bit key histogram of 4M samples ----------
__global__ void __launch_bounds__(BLK) sample_kernel(const float* __restrict__ x,
                                                     unsigned* __restrict__ ws) {
    __shared__ unsigned h[8192];
    for (int i = threadIdx.x; i < 8192; i += BLK) h[i] = 0u;
    __syncthreads();
    const float4* x4 = (const float4*)x;
    const unsigned base = blockIdx.x * 11008u;
    const int par = threadIdx.x & 1;
#pragma unroll
    for (int i = 0; i < 4; i++) {
        float4 v = x4[base + threadIdx.x + 256 * i];
        atomicAdd(&h[((f2key(v.x) >> 20) << 1) + par], 1u);
        atomicAdd(&h[((f2key(v.y) >> 20) << 1) + par], 1u);
        atomicAdd(&h[((f2key(v.z) >> 20) << 1) + par], 1u);
        atomicAdd(&h[((f2key(v.w) >> 20) << 1) + par], 1u);
    }
    __syncthreads();
    unsigned* hist = ws + OFF_H1S;
    for (int i = threadIdx.x; i < 4096; i += BLK) {
        unsigned c = h[2 * i] + h[2 * i + 1];
        if (c) atomicAdd(&hist[i], c);
    }
}

// ---------- scan_sample: coarse 2-bucket windows + below-window sample counts ----------
__global__ void __launch_bounds__(BLK) scan_sample_kernel(unsigned* __restrict__ ws) {
    __shared__ unsigned part[256];
    const unsigned* hist = ws + OFF_H1S;
    unsigned* meta = ws + OFF_META;
    int t = threadIdx.x;
    unsigned v[16];
    unsigned sum = 0u;
#pragma unroll
    for (int i = 0; i < 16; i++) { v[i] = hist[t * 16 + i]; sum += v[i]; }
    part[t] = sum;
    __syncthreads();
    for (int off = 1; off < 256; off <<= 1) {
        unsigned a = (t >= off) ? part[t - off] : 0u;
        __syncthreads();
        part[t] += a;
        __syncthreads();
    }
    unsigned incl = part[t];
    unsigned excl = incl - sum;
    unsigned ranks[2] = {RS_LO, RS_HI};
    for (int k = 0; k < 2; k++) {
        unsigned Rs = ranks[k];
        if (excl < Rs && incl >= Rs) {
            unsigned cum = excl;
            for (int i = 0; i < 16; i++) {
                if (cum + v[i] >= Rs) {
                    unsigned b = (unsigned)(t * 16 + i);
                    unsigned rel = Rs - cum;
                    unsigned wb = (2u * rel <= v[i]) ? (b > 0 ? b - 1 : 0) : b;
                    if (wb > 4094u) wb = 4094u;
                    meta[k] = wb << 20;                 // window start key
                    unsigned Cs = cum;                  // samples below bucket b
                    if (wb < b) Cs -= hist[b - 1];      // extend down one bucket
                    meta[6 + k] = Cs;                   // samples below wstart
                    break;
                }
                cum += v[i];
            }
        }
    }
}

// ---------- sample_fine: fine (4-key-bin) sample hist inside coarse windows ----------
__global__ void __launch_bounds__(BLK) sample_fine_kernel(const float* __restrict__ x,
                                                          unsigned* __restrict__ ws) {
    const unsigned w0 = __builtin_amdgcn_readfirstlane(ws[OFF_META + 0]);
    const unsigned w1 = __builtin_amdgcn_readfirstlane(ws[OFF_META + 1]);
    unsigned* f0 = ws + OFF_FLO;
    unsigned* f1 = ws + OFF_FHI;
    const float4* x4 = (const float4*)x;
    const unsigned base = blockIdx.x * 11008u;
#pragma unroll
    for (int i = 0; i < 4; i++) {
        float4 v = x4[base + threadIdx.x + 256 * i];
        float f[4] = {v.x, v.y, v.z, v.w};
#pragma unroll
        for (int c = 0; c < 4; c++) {
            unsigned key = f2key(f[c]);
            unsigned d0 = key - w0;
            if (d0 < FSPAN) atomicAdd(&f0[d0 >> 2], 1u);
            unsigned d1 = key - w1;
            if (d1 < FSPAN) atomicAdd(&f1[d1 >> 2], 1u);
        }
    }
}

// ---------- csum: 1024-entry chunk sums (generic) ----------
__global__ void __launch_bounds__(BLK) csum_kernel(const unsigned* __restrict__ src,
                                                   unsigned* __restrict__ dst) {
    const unsigned* p = src + (size_t)blockIdx.x * 1024;
    int t = threadIdx.x;
    unsigned s = p[t] + p[t + 256] + p[t + 512] + p[t + 768];
    __shared__ unsigned red[256];
    red[t] = s;
    for (int off = 128; off > 0; off >>= 1) {
        __syncthreads();
        if (t < off) red[t] += red[t + off];
    }
    if (t == 0) dst[blockIdx.x] = red[0];
}

// ---------- fine_scan: pick key cut-points [kA, kA+width) at +/-M_S sample ranks -------
__global__ void __launch_bounds__(BLK) fine_scan_kernel(unsigned* __restrict__ ws) {
    __shared__ unsigned part[256];
    __shared__ unsigned sT, sC, sR;
    __shared__ unsigned sBin[2];
    const int t = threadIdx.x;
    const int tgt = blockIdx.x;
    const unsigned* cs = ws + OFF_FCS + tgt * 512;
    unsigned c0 = cs[2 * t], c1 = cs[2 * t + 1];
    unsigned gsum = c0 + c1;
    part[t] = gsum;
    __syncthreads();
    for (int off = 1; off < 256; off <<= 1) {
        unsigned a = (t >= off) ? part[t - off] : 0u;
        __syncthreads();
        part[t] += a;
        __syncthreads();
    }
    if (t == 255) sT = part[255];
    __syncthreads();
    const unsigned T = sT;
    const unsigned incl = part[t], excl = incl - gsum;
    unsigned Rs = tgt ? RS_HI : RS_LO;
    unsigned Cs = ws[OFF_META + 6 + tgt];
    unsigned RsA = Rs - Cs;
    if (RsA < 1u) RsA = 1u;
    if (RsA > T) RsA = T;
    unsigned rA = (RsA > M_S) ? RsA - M_S : 1u;
    unsigned rB = RsA + M_S;
    if (rB > T) rB = T;

    for (int q = 0; q < 2; q++) {
        unsigned r = q ? rB : rA;
        if (excl < r && incl >= r) {
            if (excl + c0 >= r) { sC = 2u * t;      sR = r - excl; }
            else                { sC = 2u * t + 1u; sR = r - excl - c0; }
        }
        __syncthreads();
        unsigned chunk = sC, rr = sR;
        __syncthreads();
        const unsigned* hp = ws + OFF_FLO + (size_t)tgt * FBINS + (size_t)chunk * 1024;
        unsigned w[4];
        unsigned s2 = 0u;
#pragma unroll
        for (int i = 0; i < 4; i++) { w[i] = hp[t * 4 + i]; s2 += w[i]; }
        part[t] = s2;
        __syncthreads();
        for (int off = 1; off < 256; off <<= 1) {
            unsigned a = (t >= off) ? part[t - off] : 0u;
            __syncthreads();
            part[t] += a;
            __syncthreads();
        }
        unsigned incl2 = part[t], excl2 = incl2 - s2;
        if (excl2 < rr && incl2 >= rr) {
            unsigned cum = excl2;
            for (int i = 0; i < 4; i++) {
                if (cum + w[i] >= rr) { sBin[q] = chunk * 1024u + (unsigned)(t * 4 + i); break; }
                cum += w[i];
            }
        }
        __syncthreads();
    }
    if (t == 0) {
        unsigned wstart = ws[OFF_META + tgt];
        unsigned kA = wstart + sBin[0] * 4u;
        unsigned kB = wstart + (sBin[1] + 1u) * 4u;
        unsigned width = kB - kA;
        if (width > WMAX) width = WMAX;
        ws[OFF_META + 2 + 2 * tgt] = kA;
        ws[OFF_META + 3 + 2 * tgt] = width;
    }
}

// ---------- passAQ: FUSED exact-count/hist pass + quantized output write ----------
// R7: EXACT R3 kernel (fastest measured base, 114us, VGPR 24) with ONE change:
// plain cached stores instead of __builtin_nontemporal_store. Theory: NT stores
// bypass L2/L3 and appear capped ~1.6 TB/s effective write; regular stores hit
// 6.5 TB/s (fillBuffer evidence). Downside bounded: out evicts x from L3 ->
// FETCH rises ~89->~180MB (~+15us read), store side should save much more.
// (R5/R6 schedule-level attempts - prefetch, sched_barrier, staged atomics -
// were all null: compiler controls the schedule; stop fighting it.)
__global__ void __launch_bounds__(BLK) passAQ_kernel(const float* __restrict__ x,
                                                     const float* __restrict__ sl_,
                                                     const float* __restrict__ zl_,
                                                     const float* __restrict__ sh_,
                                                     const float* __restrict__ zh_,
                                                     unsigned* __restrict__ ws,
                                                     float* __restrict__ out) {
    const unsigned kAlo = __builtin_amdgcn_readfirstlane(ws[OFF_META + 2]);
    const unsigned wLo  = __builtin_amdgcn_readfirstlane(ws[OFF_META + 3]);
    const unsigned kAhi = __builtin_amdgcn_readfirstlane(ws[OFF_META + 4]);
    const unsigned wHi  = __builtin_amdgcn_readfirstlane(ws[OFF_META + 5]);
    unsigned* hLo = ws + OFF_WLO;
    unsigned* hHi = ws + OFF_WHI;

    __shared__ unsigned long long s_list[LDSCAP];
    __shared__ unsigned s_lct;
    __shared__ unsigned s_base;
    __shared__ unsigned red[256];
    if (threadIdx.x == 0) s_lct = 0u;
    __syncthreads();

    const float4* x4 = (const float4*)x;
    vfloat4* o4 = (vfloat4*)out;
    unsigned long long* list = (unsigned long long*)(ws + OFF_LIST);
    unsigned cLo = 0u, cHi = 0u;

    for (unsigned tile = blockIdx.x; tile < NTILES; tile += gridDim.x) {
        // ---- uniform per-tile row info (tile spans rows row0 .. row0+1) ----
        const unsigned eT   = tile * 4096u;                  // first element of tile
        const unsigned row0 = eT / (unsigned)COLS;           // uniform -> s_load
        const unsigned rowB = (row0 + 1u < (unsigned)ROWS) ? row0 + 1u : row0;
        const unsigned Bnd  = (row0 + 1u) * (unsigned)COLS;  // first element of next row
        const float sl0 = sl_[row0], sl1 = sl_[rowB];
        const float zl0 = zl_[row0], zl1 = zl_[rowB];
        const float sh0 = sh_[row0], sh1 = sh_[rowB];
        const float zh0 = zh_[row0], zh1 = zh_[rowB];

        const size_t base = (size_t)tile * 1024u + threadIdx.x;
        float4 vv[4];
        vv[0] = x4[base];
        vv[1] = x4[base + 256];
        vv[2] = x4[base + 512];
        vv[3] = x4[base + 768];
#pragma unroll
        for (int u = 0; u < 4; u++) {
            unsigned j  = (unsigned)(base + 256u * u);       // float4 index
            unsigned e0 = j * 4u;                            // element index of .x
            float in[4] = {vv[u].x, vv[u].y, vv[u].z, vv[u].w};
            float r[4];
#pragma unroll
            for (int c = 0; c < 4; c++) {
                float xx = in[c];
                unsigned key = f2key(xx);
                cLo += (key < kAlo) ? 1u : 0u;
                cHi += (key < kAhi) ? 1u : 0u;
                unsigned d0 = key - kAlo;
                unsigned d1 = key - kAhi;
                bool a0 = d0 < wLo;
                bool a1 = d1 < wHi;
                bool hirow = (e0 + (unsigned)c) >= Bnd;
                float sl = hirow ? sl1 : sl0;
                float zl = hirow ? zl1 : zl0;
                float sh = hirow ? sh1 : sh0;
                float zh = hirow ? zh1 : zh0;
                bool m = (key > kAlo) && (key < kAhi);       // exact when !amb
                r[c] = qdq(xx, m, sl, zl, sh, zh);
                if (__builtin_expect(a0 | a1, 0)) {          // single rare branch
                    if (a0) atomicAdd(&hLo[d0], 1u);
                    if (a1) atomicAdd(&hHi[d1], 1u);
                    unsigned pos = atomicAdd(&s_lct, 1u);    // LDS atomic: block-local
                    unsigned long long ent =
                        ((unsigned long long)__float_as_uint(xx) << 32)
                        | (unsigned long long)(e0 + (unsigned)c);
                    if (pos < LDSCAP) {
                        s_list[pos] = ent;
                    } else {                                 // safety spill (never in practice)
                        unsigned gpos = atomicAdd(&ws[OFF_LCT], 1u);
                        if (gpos < LCAP) list[gpos] = ent;
                    }
                }
            }
            vfloat4 rv = {r[0], r[1], r[2], r[3]};
            o4[j] = rv;                                      // R7: plain cached store
        }
    }

    // exact below-kA counts
    red[threadIdx.x] = cLo;
    for (int off = 128; off > 0; off >>= 1) {
        __syncthreads();
        if (threadIdx.x < off) red[threadIdx.x] += red[threadIdx.x + off];
    }
    if (threadIdx.x == 0) atomicAdd(&ws[OFF_CLO + (blockIdx.x & 63)], red[0]);
    __syncthreads();
    red[threadIdx.x] = cHi;
    for (int off = 128; off > 0; off >>= 1) {
        __syncthreads();
        if (threadIdx.x < off) red[threadIdx.x] += red[threadIdx.x + off];
    }
    if (threadIdx.x == 0) atomicAdd(&ws[OFF_CHI + (blockIdx.x & 63)], red[0]);

    // flush ambiguous list: one global atomic per block, coalesced copy
    __syncthreads();
    unsigned n = s_lct;
    if (n > LDSCAP) n = LDSCAP;
    if (threadIdx.x == 0) s_base = atomicAdd(&ws[OFF_LCT], n);
    __syncthreads();
    unsigned gbase = s_base;
    for (unsigned i = threadIdx.x; i < n; i += BLK) {
        unsigned pos = gbase + i;
        if (pos < LCAP) list[pos] = s_list[i];
    }
}

// ---------- scanB: exact rank select inside the narrow window -> thresholds ----------
__global__ void __launch_bounds__(BLK) scanB_kernel(unsigned* __restrict__ ws) {
    __shared__ unsigned part[256];
    __shared__ unsigned s_C, s_chunk, s_r;
    const int t = threadIdx.x;
    const int tgt = blockIdx.x;
    float* thr = (float*)(ws + OFF_THR);

    part[t] = (t < 64) ? ws[(tgt ? OFF_CHI : OFF_CLO) + t] : 0u;
    for (int off = 128; off > 0; off >>= 1) {
        __syncthreads();
        if (t < off) part[t] += part[t + off];
    }
    if (t == 0) s_C = part[0];
    __syncthreads();
    const unsigned RANK = tgt ? RANK_HI : RANK_LO;
    const unsigned R = RANK - s_C;    // 1-indexed residual inside window
    __syncthreads();

    const unsigned* cs = ws + OFF_WCS + tgt * 512;
    unsigned c0 = cs[2 * t], c1 = cs[2 * t + 1];
    unsigned gsum = c0 + c1;
    part[t] = gsum;
    __syncthreads();
    for (int off = 1; off < 256; off <<= 1) {
        unsigned a = (t >= off) ? part[t - off] : 0u;
        __syncthreads();
        part[t] += a;
        __syncthreads();
    }
    unsigned incl = part[t], excl = incl - gsum;
    if (excl < R && incl >= R) {
        if (excl + c0 >= R) { s_chunk = 2u * t;      s_r = R - excl; }
        else                { s_chunk = 2u * t + 1u; s_r = R - excl - c0; }
    }
    __syncthreads();
    unsigned chunk = s_chunk, rr = s_r;
    __syncthreads();

    const unsigned* hp = ws + (tgt ? OFF_WHI : OFF_WLO) + (size_t)chunk * 1024;
    unsigned w[4];
    unsigned s2 = 0u;
#pragma unroll
    for (int i = 0; i < 4; i++) { w[i] = hp[t * 4 + i]; s2 += w[i]; }
    part[t] = s2;
    __syncthreads();
    for (int off = 1; off < 256; off <<= 1) {
        unsigned a = (t >= off) ? part[t - off] : 0u;
        __syncthreads();
        part[t] += a;
        __syncthreads();
    }
    unsigned incl2 = part[t], excl2 = incl2 - s2;
    if (excl2 < rr && incl2 >= rr) {
        unsigned cum = excl2;
        for (int i = 0; i < 4; i++) {
            if (cum + w[i] >= rr) {
                unsigned key = ws[OFF_META + 2 + 2 * tgt] + chunk * 1024u + (unsigned)(t * 4 + i);
                thr[tgt] = key2f(key);
                break;
            }
            cum += w[i];
        }
    }
}

// ---------- fixup: rewrite ambiguous elements with exact thresholds ----------
__global__ void __launch_bounds__(BLK) fixup_kernel(const float* __restrict__ sl_,
                                                    const float* __restrict__ zl_,
                                                    const float* __restrict__ sh_,
                                                    const float* __restrict__ zh_,
                                                    const unsigned* __restrict__ ws,
                                                    float* __restrict__ out) {
    const float lowT  = __uint_as_float(__builtin_amdgcn_readfirstlane(ws[OFF_THR + 0]));
    const float highT = __uint_as_float(__builtin_amdgcn_readfirstlane(ws[OFF_THR + 1]));
    unsigned n = ws[OFF_LCT];
    if (n > LCAP) n = LCAP;
    const unsigned long long* list = (const unsigned long long*)(ws + OFF_LIST);

    for (unsigned i = blockIdx.x * BLK + threadIdx.x; i < n; i += gridDim.x * BLK) {
        unsigned long long p = list[i];
        unsigned idx = (unsigned)p;
        float xx = __uint_as_float((unsigned)(p >> 32));
        unsigned row = idx / (unsigned)COLS;
        bool m = (xx > lowT) && (xx < highT);   // exact reference semantics
        out[idx] = qdq(xx, m, sl_[row], zl_[row], sh_[row], zh_[row]);
    }
}

extern "C" void kernel_launch(void* const* d_in, const int* in_sizes, int n_in,
                              void* d_out, int out_size, void* d_ws, size_t ws_size,
                              hipStream_t stream) {
    const float* x  = (const float*)d_in[0];
    const float* sl = (const float*)d_in[1];
    const float* zl = (const float*)d_in[2];
    const float* sh = (const float*)d_in[3];
    const float* zh = (const float*)d_in[4];
    float* out = (float*)d_out;
    unsigned* ws = (unsigned*)d_ws;

    (void)hipMemsetAsync(d_ws, 0, (size_t)WS_ZERO * 4, stream);   // ~8.4 MB

    sample_kernel<<<1024, BLK, 0, stream>>>(x, ws);
    scan_sample_kernel<<<1, BLK, 0, stream>>>(ws);
    sample_fine_kernel<<<1024, BLK, 0, stream>>>(x, ws);
    csum_kernel<<<1024, BLK, 0, stream>>>(ws + OFF_FLO, ws + OFF_FCS);
    fine_scan_kernel<<<2, BLK, 0, stream>>>(ws);
    passAQ_kernel<<<GRID, BLK, 0, stream>>>(x, sl, zl, sh, zh, ws, out);
    csum_kernel<<<1024, BLK, 0, stream>>>(ws + OFF_WLO, ws + OFF_WCS);
    scanB_kernel<<<2, BLK, 0, stream>>>(ws);
    fixup_kernel<<<256, BLK, 0, stream>>>(sl, zl, sh, zh, ws, out);
}